// Round 1
// baseline (3766.893 us; speedup 1.0000x reference)
//
#include <hip/hip_runtime.h>
#include <cstdint>

// LSTM: SEQ=512, B=64, IN=H=1024. fp32 in/out, bf16 MFMA compute, fp32 x_proj/c.
// Layouts (from reference's .view semantics):
//   x row (b,t)   -> inp + (b*512+t)*1024
//   out[b*S*H + t*H + j] = h_t[b][j];  then h_n, c_n appended flat [b*1024+j].

typedef __bf16 bf16x8 __attribute__((ext_vector_type(8)));
typedef __bf16 bf16x4 __attribute__((ext_vector_type(4)));
typedef float  floatx4 __attribute__((ext_vector_type(4)));

#define SEQ   512
#define BATCH 64
#define HID   1024
#define GATES 4096
#define TC    128   // time-chunk for x_proj buffer (ws = B*TC*4H fp32 = 128 MB)

__device__ __forceinline__ float fast_sigm(float x) {
  return 1.0f / (1.0f + __expf(-x));
}
__device__ __forceinline__ float fast_tanh(float x) {
  x = fminf(15.0f, fmaxf(-15.0f, x));   // avoid inf/inf -> NaN
  float e = __expf(2.0f * x);
  return (e - 1.0f) / (e + 1.0f);
}

// ---------------- casts / small prep ----------------
__global__ void cast_f32_to_bf16_x4(const float* __restrict__ src,
                                    __bf16* __restrict__ dst, int n4) {
  int i = blockIdx.x * blockDim.x + threadIdx.x;
  if (i < n4) {
    float4 v = reinterpret_cast<const float4*>(src)[i];
    bf16x4 o;
    o[0] = (__bf16)v.x; o[1] = (__bf16)v.y; o[2] = (__bf16)v.z; o[3] = (__bf16)v.w;
    reinterpret_cast<bf16x4*>(dst)[i] = o;
  }
}

__global__ void bias_sum(const float* __restrict__ a, const float* __restrict__ b,
                         float* __restrict__ o) {
  int i = blockIdx.x * blockDim.x + threadIdx.x;
  if (i < GATES) o[i] = a[i] + b[i];
}

// ---------------- phase 1: x_proj chunk GEMM ----------------
// C[mt*128 + r][n] = sum_k X[(mt*512 + t0 + r)][k] * W[n][k] + bias[n]
// tile 128x128, BK=32, 4 waves (2x2), each wave 64x64 = 4x4 MFMA 16x16x32 tiles.
__global__ __launch_bounds__(256) void gemm_xproj(
    const __bf16* __restrict__ X,    // [B*SEQ][1024] bf16
    const __bf16* __restrict__ W,    // [4096][1024] bf16 (W_ih)
    const float*  __restrict__ bias, // [4096]
    float*        __restrict__ XP,   // [B*TC][4096] fp32
    int t0) {
  __shared__ __bf16 As[128][40];   // +8 pad: 2-way bank aliasing only (free)
  __shared__ __bf16 Bs[128][40];

  const int tid  = threadIdx.x;
  const int lane = tid & 63;
  const int w    = tid >> 6;
  const int wm   = w >> 1, wn = w & 1;
  const int mt   = blockIdx.x;           // = batch b (TC==tile_M==128)
  const int n0   = blockIdx.y * 128;
  const long arow0 = (long)mt * 512 + t0;

  floatx4 acc[4][4] = {};

  for (int k0 = 0; k0 < 1024; k0 += 32) {
    __syncthreads();
#pragma unroll
    for (int r = 0; r < 2; ++r) {
      int c = tid + 256 * r;          // 512 chunks of 8 bf16 per operand
      int row = c >> 2, c8 = c & 3;
      *reinterpret_cast<uint4*>(&As[row][c8 * 8]) =
          *reinterpret_cast<const uint4*>(&X[(arow0 + row) * 1024 + k0 + c8 * 8]);
      *reinterpret_cast<uint4*>(&Bs[row][c8 * 8]) =
          *reinterpret_cast<const uint4*>(&W[(long)(n0 + row) * 1024 + k0 + c8 * 8]);
    }
    __syncthreads();

    bf16x8 a[4], b[4];
#pragma unroll
    for (int i = 0; i < 4; ++i)
      a[i] = *reinterpret_cast<const __shared__ bf16x8*>(
          &As[wm * 64 + i * 16 + (lane & 15)][(lane >> 4) * 8]);
#pragma unroll
    for (int j = 0; j < 4; ++j)
      b[j] = *reinterpret_cast<const __shared__ bf16x8*>(
          &Bs[wn * 64 + j * 16 + (lane & 15)][(lane >> 4) * 8]);
#pragma unroll
    for (int i = 0; i < 4; ++i)
#pragma unroll
      for (int j = 0; j < 4; ++j)
        acc[i][j] = __builtin_amdgcn_mfma_f32_16x16x32_bf16(a[i], b[j], acc[i][j], 0, 0, 0);
  }

#pragma unroll
  for (int i = 0; i < 4; ++i) {
    int mloc = wm * 64 + i * 16 + (lane >> 4) * 4;
#pragma unroll
    for (int j = 0; j < 4; ++j) {
      int n = n0 + wn * 64 + j * 16 + (lane & 15);
      float bn = bias[n];
#pragma unroll
      for (int r = 0; r < 4; ++r)
        XP[(long)(mt * 128 + mloc + r) * 4096 + n] = acc[i][j][r] + bn;
    }
  }
}

// ---------------- phase 2: one timestep ----------------
// grid (64 j-tiles, 4 b-tiles), 256 thr. WG computes gates for 16 b x 16 j x 4 gates
// (wave w = gate w over K=1024), then the elementwise LSTM update.
__global__ __launch_bounds__(256) void lstm_step(
    const __bf16* __restrict__ hin,   // [64][1024]
    __bf16*       __restrict__ hout,  // [64][1024]
    float*        __restrict__ cst,   // [64][1024] fp32
    const __bf16* __restrict__ Whh,   // [4096][1024] bf16
    const float*  __restrict__ xp,    // chunk [B*TC][4096] fp32 (bias included)
    float*        __restrict__ out,   // full output buffer
    int t) {
  __shared__ __bf16 Hs[16][1032];    // pad: stride 516 words -> 2-way only
  __shared__ __bf16 Bs[64][264];     // pad: stride 132 words -> 2-way only
  __shared__ float  Gs[4][16][17];

  const int tid  = threadIdx.x;
  const int lane = tid & 63;
  const int w    = tid >> 6;         // gate type: 0=i 1=f 2=g 3=o
  const int j0   = blockIdx.x * 16;
  const int b0   = blockIdx.y * 16;

  // stage full h rows for this batch tile: 16 x 1024 bf16
#pragma unroll
  for (int r = 0; r < 8; ++r) {
    int c = tid + 256 * r;           // 2048 chunks of 8
    int row = c >> 7, c8 = c & 127;
    *reinterpret_cast<uint4*>(&Hs[row][c8 * 8]) =
        *reinterpret_cast<const uint4*>(&hin[(b0 + row) * 1024 + c8 * 8]);
  }

  floatx4 acc = {};
  for (int kc = 0; kc < 4; ++kc) {   // K chunks of 256
    __syncthreads();
#pragma unroll
    for (int r = 0; r < 8; ++r) {
      int c = tid + 256 * r;         // 2048 chunks of 8 (64 rows x 256)
      int rb = c >> 5, c8 = c & 31;
      int grow = (rb >> 4) * 1024 + j0 + (rb & 15);
      *reinterpret_cast<uint4*>(&Bs[rb][c8 * 8]) =
          *reinterpret_cast<const uint4*>(&Whh[(long)grow * 1024 + kc * 256 + c8 * 8]);
    }
    __syncthreads();
#pragma unroll
    for (int q = 0; q < 8; ++q) {
      bf16x8 a = *reinterpret_cast<const __shared__ bf16x8*>(
          &Hs[lane & 15][kc * 256 + q * 32 + (lane >> 4) * 8]);
      bf16x8 b = *reinterpret_cast<const __shared__ bf16x8*>(
          &Bs[w * 16 + (lane & 15)][q * 32 + (lane >> 4) * 8]);
      acc = __builtin_amdgcn_mfma_f32_16x16x32_bf16(a, b, acc, 0, 0, 0);
    }
  }

  // exchange gates through LDS: D layout col=lane&15, row=quad*4+reg
#pragma unroll
  for (int r = 0; r < 4; ++r)
    Gs[w][(lane >> 4) * 4 + r][lane & 15] = acc[r];
  __syncthreads();

  // elementwise update: one thread per (b,j) in the 16x16 tile
  int bb = tid >> 4, jj = tid & 15;
  int b = b0 + bb, j = j0 + jj;
  int tt = t & (TC - 1);
  const float* xr = &xp[((long)b * TC + tt) * 4096 + j];
  float gi = Gs[0][bb][jj] + xr[0];
  float gf = Gs[1][bb][jj] + xr[1024];
  float gg = Gs[2][bb][jj] + xr[2048];
  float go = Gs[3][bb][jj] + xr[3072];
  float c_old = cst[b * 1024 + j];
  float c_new = fast_sigm(gf) * c_old + fast_sigm(gi) * fast_tanh(gg);
  float h_new = fast_sigm(go) * fast_tanh(c_new);
  cst[b * 1024 + j]  = c_new;
  hout[b * 1024 + j] = (__bf16)h_new;
  out[(long)b * (SEQ * HID) + (long)t * HID + j] = h_new;
  if (t == SEQ - 1) {
    out[(long)SEQ * BATCH * HID + b * HID + j] = h_new;                 // h_n
    out[(long)SEQ * BATCH * HID + BATCH * HID + b * HID + j] = c_new;   // c_n
  }
}

// ---------------- host ----------------
extern "C" void kernel_launch(void* const* d_in, const int* in_sizes, int n_in,
                              void* d_out, int out_size, void* d_ws, size_t ws_size,
                              hipStream_t stream) {
  const float* inp = (const float*)d_in[0];
  const float* h0  = (const float*)d_in[1];
  const float* c0  = (const float*)d_in[2];
  const float* Wih = (const float*)d_in[3];
  const float* Whh = (const float*)d_in[4];
  const float* bih = (const float*)d_in[5];
  const float* bhh = (const float*)d_in[6];
  float* out = (float*)d_out;
  char* ws = (char*)d_ws;

  size_t off = 0;
  __bf16* Wih_b = (__bf16*)(ws + off); off += (size_t)GATES * HID * 2;        // 8 MB
  __bf16* Whh_b = (__bf16*)(ws + off); off += (size_t)GATES * HID * 2;        // 8 MB
  __bf16* x_b   = (__bf16*)(ws + off); off += (size_t)SEQ * BATCH * HID * 2;  // 64 MB
  float*  xp    = (float*)(ws + off);  off += (size_t)BATCH * TC * GATES * 4; // 128 MB
  float*  bias  = (float*)(ws + off);  off += (size_t)GATES * 4;
  float*  cst   = (float*)(ws + off);  off += (size_t)BATCH * HID * 4;
  __bf16* hb0   = (__bf16*)(ws + off); off += (size_t)BATCH * HID * 2;
  __bf16* hb1   = (__bf16*)(ws + off); off += (size_t)BATCH * HID * 2;
  if (ws_size < off) return;  // ws too small: fail cleanly (diagnosable)

  int n4;
  n4 = GATES * HID / 4;
  cast_f32_to_bf16_x4<<<(n4 + 255) / 256, 256, 0, stream>>>(Wih, Wih_b, n4);
  cast_f32_to_bf16_x4<<<(n4 + 255) / 256, 256, 0, stream>>>(Whh, Whh_b, n4);
  n4 = SEQ * BATCH * HID / 4;
  cast_f32_to_bf16_x4<<<(n4 + 255) / 256, 256, 0, stream>>>(inp, x_b, n4);
  n4 = BATCH * HID / 4;
  cast_f32_to_bf16_x4<<<(n4 + 255) / 256, 256, 0, stream>>>(h0, hb0, n4);
  bias_sum<<<GATES / 256, 256, 0, stream>>>(bih, bhh, bias);
  hipMemcpyAsync(cst, c0, (size_t)BATCH * HID * 4, hipMemcpyDeviceToDevice, stream);

  __bf16* hbuf[2] = {hb0, hb1};
  for (int chunk = 0; chunk < SEQ / TC; ++chunk) {
    int t0 = chunk * TC;
    gemm_xproj<<<dim3(BATCH, GATES / 128), 256, 0, stream>>>(x_b, Wih_b, bias, xp, t0);
    for (int tt = 0; tt < TC; ++tt) {
      int t = t0 + tt;
      lstm_step<<<dim3(HID / 16, BATCH / 16), 256, 0, stream>>>(
          hbuf[t & 1], hbuf[(t + 1) & 1], cst, Whh_b, xp, out, t);
    }
  }
}